// Round 5
// baseline (27.662 us; speedup 1.0000x reference)
//
#include <hip/hip_runtime.h>
#include <math.h>

// query [4,32,64,64] f32, key [4,32,64,192] f32
#define B 4
#define C 32
#define H 64
#define WQ 64
#define WK 192
#define NP 129                    // P = 192 - 64 + 1
#define ROWS (C * H)              // 2048 rows per batch
#define ELEMS (ROWS * WQ)         // 131072 elements per (b,p)
#define GB 256                    // blocks per batch
#define WPB 4                     // waves per block
#define RPW 2                     // rows per wave

// Kernel A: lane l owns shifts p=2l, p=2l+1 for the wave's two rows.
// k rows AND q rows are staged into a wave-private LDS slice (no SMEM in the
// loop -> pure-DS inner loop, compiler can pipeline with partial lgkmcnt).
// q reads are uniform-address ds_read broadcasts (conflict-free).
// Partials are written TRANSPOSED: part[(b*NP+p)*GB + g] for coalesced kernel-B reads.
__global__ __launch_bounds__(256, 4) void patch_l1_partial(const float* __restrict__ query,
                                                           const float* __restrict__ key,
                                                           float* __restrict__ part) {
    __shared__ __align__(16) float kbuf[WPB][RPW * WK];   // 2 rows x 192
    __shared__ __align__(16) float qbuf[WPB][RPW * WQ];   // 2 rows x 64
    __shared__ float red[WPB][NP];

    const int bid  = blockIdx.x;
    const int b    = bid >> 8;           // / GB
    const int g    = bid & (GB - 1);
    const int t    = threadIdx.x;
    const int wv   = t >> 6;
    const int lane = t & 63;
    const int slot = __builtin_amdgcn_readfirstlane(g * WPB + (t >> 6));
    const int r0   = slot * RPW;

    const float* __restrict__ kb = key   + (size_t)b * ROWS * WK + (size_t)r0 * WK;  // 384 contiguous
    const float* __restrict__ qg = query + (size_t)b * ELEMS     + (size_t)r0 * WQ;  // 128 contiguous

    // stage: lanes 0..47 carry the two k-rows, lanes 48..63 carry the two q-rows
    if (lane < 48) {
        const float4 v0 = *reinterpret_cast<const float4*>(kb + lane * 4);
        const float4 v1 = *reinterpret_cast<const float4*>(kb + WK + lane * 4);
        *reinterpret_cast<float4*>(&kbuf[wv][lane * 4])      = v0;
        *reinterpret_cast<float4*>(&kbuf[wv][WK + lane * 4]) = v1;
    } else {
        const int i = lane - 48;        // 0..15
        const float4 v0 = *reinterpret_cast<const float4*>(qg + i * 4);
        const float4 v1 = *reinterpret_cast<const float4*>(qg + WQ + i * 4);
        *reinterpret_cast<float4*>(&qbuf[wv][i * 4])      = v0;
        *reinterpret_cast<float4*>(&qbuf[wv][WQ + i * 4]) = v1;
    }

    const float* __restrict__ k0 = &kbuf[wv][0];
    const float* __restrict__ k1 = &kbuf[wv][WK];
    const float* __restrict__ q0 = &qbuf[wv][0];
    const float* __restrict__ q1 = &qbuf[wv][WQ];

    float a0 = 0.f, b0 = 0.f, a1 = 0.f, b1 = 0.f;
    float pq0 = 0.f, pq1 = 0.f;   // q[s-1] carried in registers

    #pragma unroll
    for (int si = 0; si < 33; ++si) {
        const int s = si * 2;
        const float2 ka = *reinterpret_cast<const float2*>(&k0[2 * lane + s]);
        const float2 kc = *reinterpret_cast<const float2*>(&k1[2 * lane + s]);
        if (si < 32) {
            const float2 qa = *reinterpret_cast<const float2*>(&q0[s]);   // uniform -> broadcast
            const float2 qc = *reinterpret_cast<const float2*>(&q1[s]);
            a0 += fabsf(ka.x - qa.x) + fabsf(ka.y - qa.y);
            a1 += fabsf(kc.x - qc.x) + fabsf(kc.y - qc.y);
            b0 += fabsf(ka.y - qa.x);
            b1 += fabsf(kc.y - qc.x);
            if (si > 0) {
                b0 += fabsf(ka.x - pq0);
                b1 += fabsf(kc.x - pq1);
            }
            pq0 = qa.y;
            pq1 = qc.y;
        } else {   // s = 64: only the p=2l+1 (w=63) terms
            b0 += fabsf(ka.x - pq0);
            b1 += fabsf(kc.x - pq1);
        }
    }

    // p = 128 terms: k[128+lane] vs q[lane], both rows (all from LDS)
    float acc2 = fabsf(k0[128 + lane] - q0[lane]) + fabsf(k1[128 + lane] - q1[lane]);
    #pragma unroll
    for (int m = 32; m; m >>= 1) acc2 += __shfl_xor(acc2, m, 64);

    red[wv][2 * lane]     = a0 + a1;
    red[wv][2 * lane + 1] = b0 + b1;
    if (lane == 0) red[wv][128] = acc2;
    __syncthreads();

    if (t < NP) {
        const float v = red[0][t] + red[1][t] + red[2][t] + red[3][t];
        part[((size_t)b * NP + t) * GB + g] = v;   // transposed: coalesced in kernel B
    }
}

// Kernel B: one block per batch, wave wv owns p = wv, wv+4, ... (wv0 also p=128).
// Coalesced 4x64 loads per p, butterfly wave-reduce, register min/argmin
// (increasing p + strict < keeps the first index on ties), 4-way combine in LDS.
__global__ __launch_bounds__(256) void patch_l1_final(const float* __restrict__ part,
                                                      float* __restrict__ out) {
    const int b    = blockIdx.x;
    const int t    = threadIdx.x;
    const int wv   = t >> 6;
    const int lane = t & 63;

    float best = INFINITY;
    int   besti = NP;

    for (int p = wv; p < NP; p += 4) {
        const float* __restrict__ src = part + ((size_t)b * NP + p) * GB;
        float v = src[lane] + src[lane + 64] + src[lane + 128] + src[lane + 192];
        #pragma unroll
        for (int m = 32; m; m >>= 1) v += __shfl_xor(v, m, 64);
        const float y = v * (1.0f / (float)ELEMS);
        if (y < best) { best = y; besti = p; }
    }

    __shared__ float sy[4];
    __shared__ int   si[4];
    if (lane == 0) { sy[wv] = best; si[wv] = besti; }
    __syncthreads();

    if (t == 0) {
        float yb = sy[0];
        int   ib = si[0];
        #pragma unroll
        for (int w = 1; w < 4; ++w) {
            const float yo = sy[w];
            const int   io = si[w];
            if (yo < yb || (yo == yb && io < ib)) { yb = yo; ib = io; }
        }
        out[b]     = (float)ib;
        out[5 + b] = yb;
        if (b == 0) out[4] = (float)NP;
    }
}

extern "C" void kernel_launch(void* const* d_in, const int* in_sizes, int n_in,
                              void* d_out, int out_size, void* d_ws, size_t ws_size,
                              hipStream_t stream) {
    const float* query = (const float*)d_in[0];
    const float* key   = (const float*)d_in[1];
    float* out  = (float*)d_out;
    float* part = (float*)d_ws;   // B*NP*GB floats = 528 KB, block-owned (no atomics)

    patch_l1_partial<<<B * GB, 256, 0, stream>>>(query, key, part);
    patch_l1_final<<<B, 256, 0, stream>>>(part, out);
}